// Round 1
// baseline (308.541 us; speedup 1.0000x reference)
//
#include <hip/hip_runtime.h>
#include <hip/hip_bf16.h>
#include <stdint.h>

// B=1024, D_IN=2048, D_H=4096, D_OUT=2048, D_INT=1024
// L_W = 2^23 for both weight fastfoods; L_b1=4096, L_b2=2048. LL==DD everywhere.

typedef __attribute__((ext_vector_type(8))) short bf16x8;   // 8 bf16 (4 VGPRs)
typedef __attribute__((ext_vector_type(4))) float f32x4;

__device__ __forceinline__ ushort f2bf(float f) {           // RNE f32->bf16
  union { float f; uint32_t u; } v; v.f = f;
  return (ushort)((v.u + 0x7FFFu + ((v.u >> 16) & 1u)) >> 16);
}

__device__ __forceinline__ void gload_lds16(const void* g, void* l) {
  __builtin_amdgcn_global_load_lds(
      (const __attribute__((address_space(1))) void*)g,
      (__attribute__((address_space(3))) void*)l, 16, 0, 0);
}

// ---------------- t = WHT_1024(BB[0:1024] * V) for W1 (block 0) and W2 (block 1)
__global__ __launch_bounds__(256) void make_t_kernel(
    const float* __restrict__ V, const float* __restrict__ BB1,
    const float* __restrict__ BB2, float* __restrict__ t1, float* __restrict__ t2) {
  __shared__ float ts[1024];
  const float* BB = blockIdx.x ? BB2 : BB1;
  float* t = blockIdx.x ? t2 : t1;
  int tid = threadIdx.x;
  for (int i = tid; i < 1024; i += 256) ts[i] = BB[i] * V[i];
  for (int st = 0; st < 10; ++st) {
    int half = 1 << st;
    __syncthreads();
    for (int j = tid; j < 512; j += 256) {
      int p = ((j >> st) << (st + 1)) | (j & (half - 1));
      float a = ts[p], b = ts[p + half];
      ts[p] = a + b; ts[p + half] = a - b;
    }
  }
  __syncthreads();
  for (int i = tid; i < 1024; i += 256) t[i] = ts[i];
}

// ---------------- full fastfood for biases: block 0 -> b1 (L=4096), block 1 -> b2 (L=2048)
__global__ __launch_bounds__(256) void make_bias_kernel(
    const float* __restrict__ V,
    const float* __restrict__ BB1, const int* __restrict__ Pi1, const float* __restrict__ GG1, const float* __restrict__ b10,
    const float* __restrict__ BB2, const int* __restrict__ Pi2, const float* __restrict__ GG2, const float* __restrict__ b20,
    float* __restrict__ ob1, float* __restrict__ ob2) {
  __shared__ float ts[1024];
  __shared__ float zs[4096];
  __shared__ float red[4];
  int tid = threadIdx.x;
  int which = blockIdx.x;
  int L = which ? 2048 : 4096;
  const float* BB = which ? BB2 : BB1;
  const int* Pi = which ? Pi2 : Pi1;
  const float* GG = which ? GG2 : GG1;
  const float* b0 = which ? b20 : b10;
  float* ob = which ? ob2 : ob1;

  for (int i = tid; i < 1024; i += 256) ts[i] = BB[i] * V[i];
  for (int st = 0; st < 10; ++st) {
    int half = 1 << st;
    __syncthreads();
    for (int j = tid; j < 512; j += 256) {
      int p = ((j >> st) << (st + 1)) | (j & (half - 1));
      float a = ts[p], b = ts[p + half];
      ts[p] = a + b; ts[p + half] = a - b;
    }
  }
  __syncthreads();
  float gsum = 0.f;
  for (int i = tid; i < L; i += 256) {
    int pi = Pi[i];
    float g = GG[i];
    gsum += g * g;
    zs[i] = ts[pi & 1023] * g;
  }
  for (int o = 32; o > 0; o >>= 1) gsum += __shfl_down(gsum, o);
  if ((tid & 63) == 0) red[tid >> 6] = gsum;
  __syncthreads();
  float ssum = red[0] + red[1] + red[2] + red[3];
  for (int st = 0; (1 << st) < L; ++st) {
    int half = 1 << st;
    __syncthreads();
    for (int j = tid; j < (L >> 1); j += 256) {
      int p = ((j >> st) << (st + 1)) | (j & (half - 1));
      float a = zs[p], b = zs[p + half];
      zs[p] = a + b; zs[p + half] = a - b;
    }
  }
  __syncthreads();
  float scale = rsqrtf((float)L * ssum);
  for (int i = tid; i < L; i += 256) ob[i] = b0[i] + zs[i] * scale;
}

// ---------------- pass 1: z = t[Pi&1023]*GG, WHT_8192 on contiguous blocks (bits 0..12),
// plus per-block partial sum of GG^2.
__global__ __launch_bounds__(256) void ff_pass1(
    const int* __restrict__ Pi, const float* __restrict__ GG,
    const float* __restrict__ t, float* __restrict__ inter, float* __restrict__ partials) {
  __shared__ float ts[1024];
  __shared__ float zs[8192];
  __shared__ float red[4];
  int tid = threadIdx.x;
  size_t base = (size_t)blockIdx.x * 8192;
  for (int i = tid; i < 1024; i += 256) ts[i] = t[i];
  __syncthreads();
  float gsum = 0.f;
  for (int i = tid; i < 8192; i += 256) {
    int pi = Pi[base + i];
    float g = GG[base + i];
    gsum += g * g;
    zs[i] = ts[pi & 1023] * g;
  }
  for (int o = 32; o > 0; o >>= 1) gsum += __shfl_down(gsum, o);
  if ((tid & 63) == 0) red[tid >> 6] = gsum;
  __syncthreads();
  if (tid == 0) partials[blockIdx.x] = red[0] + red[1] + red[2] + red[3];
  for (int st = 0; st < 13; ++st) {
    int half = 1 << st;
    for (int j = tid; j < 4096; j += 256) {
      int p = ((j >> st) << (st + 1)) | (j & (half - 1));
      float a = zs[p], b = zs[p + half];
      zs[p] = a + b; zs[p + half] = a - b;
    }
    __syncthreads();
  }
  for (int i = tid; i < 8192; i += 256) inter[base + i] = zs[i];
}

// ---------------- finalize scale = 1/sqrt(L * sum(G^2))
__global__ __launch_bounds__(256) void reduce_scale(
    const float* __restrict__ partials, int n, float L, float* __restrict__ scale_out) {
  __shared__ float red[4];
  int tid = threadIdx.x;
  float s = 0.f;
  for (int i = tid; i < n; i += 256) s += partials[i];
  for (int o = 32; o > 0; o >>= 1) s += __shfl_down(s, o);
  if ((tid & 63) == 0) red[tid >> 6] = s;
  __syncthreads();
  if (tid == 0) scale_out[0] = rsqrtf(L * (red[0] + red[1] + red[2] + red[3]));
}

// ---------------- pass 2: WHT_1024 across stride 8192 (bits 13..22), fused
// epilogue W = W0 + m5*scale, converted to bf16. Tile: 1024 rows x 32 cols (128 KiB LDS).
__global__ __launch_bounds__(1024) void ff_pass2(
    const float* __restrict__ inter, const float* __restrict__ W0,
    const float* __restrict__ scale_p, ushort* __restrict__ Wb) {
  __shared__ float tile[1024 * 32];
  int tid = threadIdx.x;
  int cb = blockIdx.x * 32;
  for (int it = 0; it < 32; ++it) {
    int e = it * 1024 + tid;           // e == r*32 + c
    tile[e] = inter[(size_t)(e >> 5) * 8192 + cb + (e & 31)];
  }
  __syncthreads();
  int c = tid & 31, jt = tid >> 5;
  for (int st = 0; st < 10; ++st) {
    int half = 1 << st;
    for (int j = jt; j < 512; j += 32) {
      int p = ((j >> st) << (st + 1)) | (j & (half - 1));
      float a = tile[p * 32 + c], b = tile[(p + half) * 32 + c];
      tile[p * 32 + c] = a + b; tile[(p + half) * 32 + c] = a - b;
    }
    __syncthreads();
  }
  float sc = *scale_p;
  for (int it = 0; it < 32; ++it) {
    int e = it * 1024 + tid;
    size_t g = (size_t)(e >> 5) * 8192 + cb + (e & 31);
    Wb[g] = f2bf(tile[e] * sc + W0[g]);
  }
}

// ---------------- x (f32) -> bf16
__global__ __launch_bounds__(256) void cvt_f32_bf16(
    const float4* __restrict__ in, ushort4* __restrict__ out, int n4) {
  int i = blockIdx.x * 256 + threadIdx.x;
  if (i < n4) {
    float4 v = in[i];
    ushort4 o;
    o.x = f2bf(v.x); o.y = f2bf(v.y); o.z = f2bf(v.z); o.w = f2bf(v.w);
    out[i] = o;
  }
}

// ---------------- C = A * B^T  (A: MxK bf16 row-major, B: NxK bf16 row-major)
// 128x128 tile, BK=64, 4 waves (2x2), each wave 64x64 = 4x4 frags of 16x16x32 MFMA.
// EPI==0: C = bf16(relu(acc + bias))  -> Cb ;  EPI==1: C = f32(acc + bias) -> Cf
template <int EPI>
__global__ __launch_bounds__(256) void gemm_bt(
    const ushort* __restrict__ A, const ushort* __restrict__ B,
    const float* __restrict__ bias, ushort* __restrict__ Cb, float* __restrict__ Cf,
    int M, int N, int K) {
  __shared__ ushort As[128 * 64];
  __shared__ ushort Bs[128 * 64];
  const int tid = threadIdx.x;
  const int w = tid >> 6, l = tid & 63;
  const int wr = w >> 1, wc = w & 1;
  const int brow = blockIdx.y << 7, bcol = blockIdx.x << 7;
  const int lrow = l >> 3;          // 0..7  (row within 8-row chunk)
  const int lk = (l & 7) << 3;      // 0..56 (k offset, x8 bf16 = 16B)
  const int l15 = l & 15;
  const int kq = (l >> 4) << 3;     // k-quadrant base for MFMA fragments
  f32x4 acc[4][4] = {};

  for (int k0 = 0; k0 < K; k0 += 64) {
#pragma unroll
    for (int i = 0; i < 4; ++i) {
      int ch = (w << 2) + i;        // chunk 0..15, 8 rows of 64 bf16 each
      int row = (ch << 3) + lrow;   // 0..127
      gload_lds16(A + (size_t)(brow + row) * K + k0 + lk, As + (ch << 9));
      gload_lds16(B + (size_t)(bcol + row) * K + k0 + lk, Bs + (ch << 9));
    }
    __syncthreads();
#pragma unroll
    for (int kk = 0; kk < 2; ++kk) {
      bf16x8 af[4], bfr[4];
#pragma unroll
      for (int m = 0; m < 4; ++m)
        af[m] = *(const bf16x8*)(As + ((wr << 6) + (m << 4) + l15) * 64 + (kk << 5) + kq);
#pragma unroll
      for (int n = 0; n < 4; ++n)
        bfr[n] = *(const bf16x8*)(Bs + ((wc << 6) + (n << 4) + l15) * 64 + (kk << 5) + kq);
#pragma unroll
      for (int m = 0; m < 4; ++m)
#pragma unroll
        for (int n = 0; n < 4; ++n)
          acc[m][n] = __builtin_amdgcn_mfma_f32_16x16x32_bf16(af[m], bfr[n], acc[m][n], 0, 0, 0);
    }
    __syncthreads();
  }

#pragma unroll
  for (int n = 0; n < 4; ++n) {
    int col = bcol + (wc << 6) + (n << 4) + l15;
    float bv = bias[col];
#pragma unroll
    for (int m = 0; m < 4; ++m) {
      int row0 = brow + (wr << 6) + (m << 4) + ((l >> 4) << 2);
#pragma unroll
      for (int j = 0; j < 4; ++j) {
        float v = acc[m][n][j] + bv;
        if (EPI == 0) {
          v = fmaxf(v, 0.f);
          Cb[(size_t)(row0 + j) * N + col] = f2bf(v);
        } else {
          Cf[(size_t)(row0 + j) * N + col] = v;
        }
      }
    }
  }
}

extern "C" void kernel_launch(void* const* d_in, const int* in_sizes, int n_in,
                              void* d_out, int out_size, void* d_ws, size_t ws_size,
                              hipStream_t stream) {
  const float* x     = (const float*)d_in[0];
  const float* V     = (const float*)d_in[1];
  const float* W1_0  = (const float*)d_in[2];
  const float* b1_0  = (const float*)d_in[3];
  const float* W2_0  = (const float*)d_in[4];
  const float* b2_0  = (const float*)d_in[5];
  const float* BB_W1 = (const float*)d_in[6];
  const int*   Pi_W1 = (const int*)d_in[7];
  const float* GG_W1 = (const float*)d_in[8];
  const float* BB_b1 = (const float*)d_in[9];
  const int*   Pi_b1 = (const int*)d_in[10];
  const float* GG_b1 = (const float*)d_in[11];
  const float* BB_W2 = (const float*)d_in[12];
  const int*   Pi_W2 = (const int*)d_in[13];
  const float* GG_W2 = (const float*)d_in[14];
  const float* BB_b2 = (const float*)d_in[15];
  const int*   Pi_b2 = (const int*)d_in[16];
  const float* GG_b2 = (const float*)d_in[17];
  float* out = (float*)d_out;

  // workspace layout (needs ~76 MB)
  char* ws = (char*)d_ws;
  float*  inter = (float*)(ws);                          // 32 MB (reused W1 then W2)
  ushort* W1b   = (ushort*)(ws + 33554432ull);           // 16 MB
  ushort* W2b   = (ushort*)(ws + 50331648ull);           // 16 MB
  ushort* xb    = (ushort*)(ws + 67108864ull);           //  4 MB
  ushort* hb    = (ushort*)(ws + 71303168ull);           //  8 MB
  float*  t1    = (float*)(ws + 79691776ull);            //  4 KB
  float*  t2    = (float*)(ws + 79695872ull);            //  4 KB
  float*  b1    = (float*)(ws + 79699968ull);            // 16 KB
  float*  b2    = (float*)(ws + 79716352ull);            //  8 KB
  float*  parts = (float*)(ws + 79724544ull);            //  4 KB
  float*  sc1   = (float*)(ws + 79728640ull);
  float*  sc2   = (float*)(ws + 79728704ull);

  make_t_kernel<<<2, 256, 0, stream>>>(V, BB_W1, BB_W2, t1, t2);
  make_bias_kernel<<<2, 256, 0, stream>>>(V, BB_b1, Pi_b1, GG_b1, b1_0,
                                          BB_b2, Pi_b2, GG_b2, b2_0, b1, b2);
  cvt_f32_bf16<<<2048, 256, 0, stream>>>((const float4*)x, (ushort4*)xb, 524288);

  ff_pass1<<<1024, 256, 0, stream>>>(Pi_W1, GG_W1, t1, inter, parts);
  reduce_scale<<<1, 256, 0, stream>>>(parts, 1024, 8388608.f, sc1);
  ff_pass2<<<256, 1024, 0, stream>>>(inter, W1_0, sc1, W1b);

  ff_pass1<<<1024, 256, 0, stream>>>(Pi_W2, GG_W2, t2, inter, parts);
  reduce_scale<<<1, 256, 0, stream>>>(parts, 1024, 8388608.f, sc2);
  ff_pass2<<<256, 1024, 0, stream>>>(inter, W2_0, sc2, W2b);

  // h = relu(x @ W1^T + b1)  -> bf16 ; out = h @ W2^T + b2 -> f32
  gemm_bt<0><<<dim3(32, 8), 256, 0, stream>>>(xb, W1b, b1, hb, nullptr, 1024, 4096, 2048);
  gemm_bt<1><<<dim3(16, 8), 256, 0, stream>>>(hb, W2b, b2, nullptr, out, 1024, 2048, 4096);
}

// Round 2
// 184.798 us; speedup vs baseline: 1.6696x; 1.6696x over previous
//
#include <hip/hip_runtime.h>
#include <hip/hip_bf16.h>
#include <stdint.h>

// B=1024, D_IN=2048, D_H=4096, D_OUT=2048, D_INT=1024
// L_W = 2^23 for both weight fastfoods; L_b1=4096, L_b2=2048. LL==DD everywhere.

typedef __attribute__((ext_vector_type(8))) short bf16x8;   // 8 bf16 (4 VGPRs)
typedef __attribute__((ext_vector_type(4))) float f32x4;

__device__ __forceinline__ ushort f2bf(float f) {           // RNE f32->bf16
  union { float f; uint32_t u; } v; v.f = f;
  return (ushort)((v.u + 0x7FFFu + ((v.u >> 16) & 1u)) >> 16);
}
__device__ __forceinline__ float bf2f(ushort u) {
  union { uint32_t u; float f; } v; v.u = (uint32_t)u << 16; return v.f;
}

__device__ __forceinline__ void gload_lds16(const void* g, void* l) {
  __builtin_amdgcn_global_load_lds(
      (const __attribute__((address_space(1))) void*)g,
      (__attribute__((address_space(3))) void*)l, 16, 0, 0);
}

template <int NN>
__device__ __forceinline__ void wht_inreg(float* v) {
#pragma unroll
  for (int h = 1; h < NN; h <<= 1)
#pragma unroll
    for (int g = 0; g < NN; g += (h << 1))
#pragma unroll
      for (int k = 0; k < h; ++k) {
        float a = v[g + k], b = v[g + k + h];
        v[g + k] = a + b; v[g + k + h] = a - b;
      }
}

// ---------------- t = WHT_1024(BB[0:1024] * V) for W1 (block 0) and W2 (block 1)
__global__ __launch_bounds__(256) void make_t_kernel(
    const float* __restrict__ V, const float* __restrict__ BB1,
    const float* __restrict__ BB2, float* __restrict__ t1, float* __restrict__ t2) {
  __shared__ float ts[1024];
  const float* BB = blockIdx.x ? BB2 : BB1;
  float* t = blockIdx.x ? t2 : t1;
  int tid = threadIdx.x;
  for (int i = tid; i < 1024; i += 256) ts[i] = BB[i] * V[i];
  for (int st = 0; st < 10; ++st) {
    int half = 1 << st;
    __syncthreads();
    for (int j = tid; j < 512; j += 256) {
      int p = ((j >> st) << (st + 1)) | (j & (half - 1));
      float a = ts[p], b = ts[p + half];
      ts[p] = a + b; ts[p + half] = a - b;
    }
  }
  __syncthreads();
  for (int i = tid; i < 1024; i += 256) t[i] = ts[i];
}

// ---------------- full fastfood for biases: block 0 -> b1 (L=4096), block 1 -> b2 (L=2048)
__global__ __launch_bounds__(256) void make_bias_kernel(
    const float* __restrict__ V,
    const float* __restrict__ BB1, const int* __restrict__ Pi1, const float* __restrict__ GG1, const float* __restrict__ b10,
    const float* __restrict__ BB2, const int* __restrict__ Pi2, const float* __restrict__ GG2, const float* __restrict__ b20,
    float* __restrict__ ob1, float* __restrict__ ob2) {
  __shared__ float ts[1024];
  __shared__ float zs[4096];
  __shared__ float red[4];
  int tid = threadIdx.x;
  int which = blockIdx.x;
  int L = which ? 2048 : 4096;
  const float* BB = which ? BB2 : BB1;
  const int* Pi = which ? Pi2 : Pi1;
  const float* GG = which ? GG2 : GG1;
  const float* b0 = which ? b20 : b10;
  float* ob = which ? ob2 : ob1;

  for (int i = tid; i < 1024; i += 256) ts[i] = BB[i] * V[i];
  for (int st = 0; st < 10; ++st) {
    int half = 1 << st;
    __syncthreads();
    for (int j = tid; j < 512; j += 256) {
      int p = ((j >> st) << (st + 1)) | (j & (half - 1));
      float a = ts[p], b = ts[p + half];
      ts[p] = a + b; ts[p + half] = a - b;
    }
  }
  __syncthreads();
  float gsum = 0.f;
  for (int i = tid; i < L; i += 256) {
    int pi = Pi[i];
    float g = GG[i];
    gsum += g * g;
    zs[i] = ts[pi & 1023] * g;
  }
  for (int o = 32; o > 0; o >>= 1) gsum += __shfl_down(gsum, o);
  if ((tid & 63) == 0) red[tid >> 6] = gsum;
  __syncthreads();
  float ssum = red[0] + red[1] + red[2] + red[3];
  for (int st = 0; (1 << st) < L; ++st) {
    int half = 1 << st;
    __syncthreads();
    for (int j = tid; j < (L >> 1); j += 256) {
      int p = ((j >> st) << (st + 1)) | (j & (half - 1));
      float a = zs[p], b = zs[p + half];
      zs[p] = a + b; zs[p + half] = a - b;
    }
  }
  __syncthreads();
  float scale = rsqrtf((float)L * ssum);
  for (int i = tid; i < L; i += 256) ob[i] = b0[i] + zs[i] * scale;
}

// ---------------- pass 1: z = t[Pi&1023]*GG, WHT_8192 on contiguous 8192-blocks
// (bits 0..12) via 3 radix-32/8 register passes; skewed LDS slot = i + (i>>5)
// keeps every pass <=2-way (free). Writes inter as bf16 + per-block GG^2 partial.
__global__ __launch_bounds__(256) void ff_pass1(
    const int* __restrict__ Pi, const float* __restrict__ GG,
    const float* __restrict__ t, ushort* __restrict__ inter, float* __restrict__ partials) {
  __shared__ float ts[1024];
  __shared__ float zs[8448];        // 8192 + skew
  __shared__ float red[4];
  int tid = threadIdx.x;
  size_t base = (size_t)blockIdx.x * 8192;
  for (int i = tid; i < 1024; i += 256) ts[i] = t[i];
  __syncthreads();
  float gsum = 0.f;
#pragma unroll 8
  for (int ii = 0; ii < 32; ++ii) {
    int i = ii * 256 + tid;
    int pi = Pi[base + i];
    float g = GG[base + i];
    gsum += g * g;
    zs[i + (i >> 5)] = ts[pi & 1023] * g;
  }
  for (int o = 32; o > 0; o >>= 1) gsum += __shfl_down(gsum, o);
  if ((tid & 63) == 0) red[tid >> 6] = gsum;
  __syncthreads();                   // covers zs gather + red
  if (tid == 0) partials[blockIdx.x] = red[0] + red[1] + red[2] + red[3];

  float v[32];
  // pass A: bits 0-4 (32 consecutive elems per thread)
  {
    int b0 = tid << 5;
#pragma unroll
    for (int r = 0; r < 32; ++r) { int i = b0 + r; v[r] = zs[i + (i >> 5)]; }
    wht_inreg<32>(v);
#pragma unroll
    for (int r = 0; r < 32; ++r) { int i = b0 + r; zs[i + (i >> 5)] = v[r]; }
  }
  __syncthreads();
  // pass B: bits 5-9
  {
    int lo = tid & 31, hi = tid >> 5;
#pragma unroll
    for (int r = 0; r < 32; ++r) { int i = lo | (r << 5) | (hi << 10); v[r] = zs[i + (i >> 5)]; }
    wht_inreg<32>(v);
#pragma unroll
    for (int r = 0; r < 32; ++r) { int i = lo | (r << 5) | (hi << 10); zs[i + (i >> 5)] = v[r]; }
  }
  __syncthreads();
  // pass C: bits 10-12 (4 groups of 8) + fused bf16 write-out (coalesced on tid)
  {
    float w[32];
#pragma unroll
    for (int q = 0; q < 4; ++q)
#pragma unroll
      for (int r = 0; r < 8; ++r) { int i = tid + (q << 8) + (r << 10); w[q * 8 + r] = zs[i + (i >> 5)]; }
#pragma unroll
    for (int q = 0; q < 4; ++q) wht_inreg<8>(w + 8 * q);
#pragma unroll
    for (int q = 0; q < 4; ++q)
#pragma unroll
      for (int r = 0; r < 8; ++r)
        inter[base + tid + (q << 8) + (r << 10)] = f2bf(w[q * 8 + r]);
  }
}

// ---------------- pass 2: WHT_1024 across stride 8192 (bits 13..22) on a
// [1024 rows x 32 cols] tile (stride 33 f32 in LDS), 2 radix-32 register passes.
// Scale computed in-kernel from partials; epilogue W = W0 + m5*scale -> bf16.
__global__ __launch_bounds__(1024) void ff_pass2(
    const ushort* __restrict__ inter, const float* __restrict__ W0,
    const float* __restrict__ partials, ushort* __restrict__ Wb) {
  __shared__ float tile[1024 * 33];
  __shared__ float red2[16];
  int tid = threadIdx.x;
  int cb = blockIdx.x * 32;
  float s = partials[tid];
  for (int o = 32; o > 0; o >>= 1) s += __shfl_down(s, o);
  if ((tid & 63) == 0) red2[tid >> 6] = s;
  // load tile: 8192 ushort4 (8B) reads
#pragma unroll
  for (int it = 0; it < 8; ++it) {
    int u = it * 1024 + tid;
    int row = u >> 3, c4 = u & 7;
    ushort4 d = *(const ushort4*)(inter + (size_t)row * 8192 + cb + (c4 << 2));
    float* tp = &tile[row * 33 + (c4 << 2)];
    tp[0] = bf2f(d.x); tp[1] = bf2f(d.y); tp[2] = bf2f(d.z); tp[3] = bf2f(d.w);
  }
  __syncthreads();
  float ssum = 0.f;
#pragma unroll
  for (int k = 0; k < 16; ++k) ssum += red2[k];
  float sc = rsqrtf(8388608.f * ssum);

  float v[32];
  int c = tid & 31, g = tid >> 5;
  // pass A: row bits 0-4 (rows 32g+r)
#pragma unroll
  for (int r = 0; r < 32; ++r) v[r] = tile[(32 * g + r) * 33 + c];
  wht_inreg<32>(v);
#pragma unroll
  for (int r = 0; r < 32; ++r) tile[(32 * g + r) * 33 + c] = v[r];
  __syncthreads();
  // pass B: row bits 5-9 (rows (r<<5)+g) + fused epilogue
#pragma unroll
  for (int r = 0; r < 32; ++r) v[r] = tile[((r << 5) + g) * 33 + c];
  wht_inreg<32>(v);
#pragma unroll
  for (int r = 0; r < 32; ++r) {
    size_t gg = (size_t)((r << 5) + g) * 8192 + cb + c;
    Wb[gg] = f2bf(v[r] * sc + W0[gg]);
  }
}

// ---------------- x (f32) -> bf16
__global__ __launch_bounds__(256) void cvt_f32_bf16(
    const float4* __restrict__ in, ushort4* __restrict__ out, int n4) {
  int i = blockIdx.x * 256 + threadIdx.x;
  if (i < n4) {
    float4 v = in[i];
    ushort4 o;
    o.x = f2bf(v.x); o.y = f2bf(v.y); o.z = f2bf(v.z); o.w = f2bf(v.w);
    out[i] = o;
  }
}

// ---------------- C = A * B^T  (A: MxK bf16 row-major, B: NxK bf16 row-major)
// 128x128 tile, BK=64, 4 waves (2x2), each wave 64x64 = 4x4 frags of 16x16x32.
// Double-buffered LDS with prefetch (one barrier per K-step); both-sides XOR
// swizzle (src col8 ^= row&7 on the global address, same XOR on ds_read).
// blockIdx.z = K-split chunk (nt K-steps each).
// EPI==0: C = bf16(relu(acc + bias)) -> Cb ;  EPI==1: f32 partial -> Cf[z]
template <int EPI>
__global__ __launch_bounds__(256) void gemm_bt(
    const ushort* __restrict__ A, const ushort* __restrict__ B,
    const float* __restrict__ bias, ushort* __restrict__ Cb, float* __restrict__ Cf,
    int M, int N, int K, int nt) {
  __shared__ ushort As[2][128 * 64];
  __shared__ ushort Bs[2][128 * 64];
  const int tid = threadIdx.x;
  const int w = tid >> 6, l = tid & 63;
  const int wr = w >> 1, wc = w & 1;
  const int brow = blockIdx.y << 7, bcol = blockIdx.x << 7;
  const int lrow = l >> 3;                       // row within 8-row chunk
  const int csrc = ((l & 7) ^ lrow) << 3;        // swizzled source col (ushort)
  const int l15 = l & 15;
  const int x7 = l15 & 7;
  const int kb = blockIdx.z * (nt << 6);
  f32x4 acc[4][4] = {};

  const ushort* pa = A + (size_t)(brow + (w << 5) + lrow) * K + kb + csrc;
  const ushort* pb = B + (size_t)(bcol + (w << 5) + lrow) * K + kb + csrc;
  const size_t K8 = (size_t)K << 3;

#define STAGE(buf, tt)                                                      \
  {                                                                         \
    const ushort* qa = pa + ((tt) << 6);                                    \
    const ushort* qb = pb + ((tt) << 6);                                    \
    _Pragma("unroll")                                                       \
    for (int i = 0; i < 4; ++i) {                                           \
      gload_lds16(qa + K8 * i, &As[buf][(((w << 2) + i) << 9)]);            \
      gload_lds16(qb + K8 * i, &Bs[buf][(((w << 2) + i) << 9)]);            \
    }                                                                       \
  }

  STAGE(0, 0);
  __syncthreads();
  for (int t = 0; t < nt; ++t) {
    int cur = t & 1;
    if (t + 1 < nt) STAGE(cur ^ 1, t + 1);
#pragma unroll
    for (int kk = 0; kk < 2; ++kk) {
      bf16x8 af[4], bfr[4];
      int c8 = (kk << 2) + (l >> 4);
#pragma unroll
      for (int m = 0; m < 4; ++m) {
        int ra = (wr << 6) + (m << 4) + l15;
        af[m] = *(const bf16x8*)&As[cur][(ra << 6) + ((c8 ^ x7) << 3)];
      }
#pragma unroll
      for (int n = 0; n < 4; ++n) {
        int rb = (wc << 6) + (n << 4) + l15;
        bfr[n] = *(const bf16x8*)&Bs[cur][(rb << 6) + ((c8 ^ x7) << 3)];
      }
#pragma unroll
      for (int m = 0; m < 4; ++m)
#pragma unroll
        for (int n = 0; n < 4; ++n)
          acc[m][n] = __builtin_amdgcn_mfma_f32_16x16x32_bf16(af[m], bfr[n], acc[m][n], 0, 0, 0);
    }
    __syncthreads();
  }
#undef STAGE

  if (EPI == 0) {
#pragma unroll
    for (int n = 0; n < 4; ++n) {
      int col = bcol + (wc << 6) + (n << 4) + l15;
      float bv = bias[col];
#pragma unroll
      for (int m = 0; m < 4; ++m) {
        int row0 = brow + (wr << 6) + (m << 4) + ((l >> 4) << 2);
#pragma unroll
        for (int j = 0; j < 4; ++j) {
          float vv = fmaxf(acc[m][n][j] + bv, 0.f);
          Cb[(size_t)(row0 + j) * N + col] = f2bf(vv);
        }
      }
    }
  } else {
    float* outp = Cf + (size_t)blockIdx.z * M * N;
#pragma unroll
    for (int n = 0; n < 4; ++n) {
      int col = bcol + (wc << 6) + (n << 4) + l15;
#pragma unroll
      for (int m = 0; m < 4; ++m) {
        int row0 = brow + (wr << 6) + (m << 4) + ((l >> 4) << 2);
#pragma unroll
        for (int j = 0; j < 4; ++j)
          outp[(size_t)(row0 + j) * N + col] = acc[m][n][j];
      }
    }
  }
}

// ---------------- out = P0 + P1 + b2   (1024x2048 f32, vectorized f4)
__global__ __launch_bounds__(256) void reduce_out(
    const float4* __restrict__ P, const float* __restrict__ b2,
    float4* __restrict__ out) {
  int i = blockIdx.x * 256 + threadIdx.x;         // 524288 f4
  float4 a = P[i], b = P[i + 524288];
  const float4 bb = *(const float4*)(b2 + ((i & 511) << 2));
  float4 o;
  o.x = a.x + b.x + bb.x; o.y = a.y + b.y + bb.y;
  o.z = a.z + b.z + bb.z; o.w = a.w + b.w + bb.w;
  out[i] = o;
}

extern "C" void kernel_launch(void* const* d_in, const int* in_sizes, int n_in,
                              void* d_out, int out_size, void* d_ws, size_t ws_size,
                              hipStream_t stream) {
  const float* x     = (const float*)d_in[0];
  const float* V     = (const float*)d_in[1];
  const float* W1_0  = (const float*)d_in[2];
  const float* b1_0  = (const float*)d_in[3];
  const float* W2_0  = (const float*)d_in[4];
  const float* b2_0  = (const float*)d_in[5];
  const float* BB_W1 = (const float*)d_in[6];
  const int*   Pi_W1 = (const int*)d_in[7];
  const float* GG_W1 = (const float*)d_in[8];
  const float* BB_b1 = (const float*)d_in[9];
  const int*   Pi_b1 = (const int*)d_in[10];
  const float* GG_b1 = (const float*)d_in[11];
  const float* BB_W2 = (const float*)d_in[12];
  const int*   Pi_W2 = (const int*)d_in[13];
  const float* GG_W2 = (const float*)d_in[14];
  const float* BB_b2 = (const float*)d_in[15];
  const int*   Pi_b2 = (const int*)d_in[16];
  const float* GG_b2 = (const float*)d_in[17];
  float* out = (float*)d_out;

  const size_t MB = 1048576ull;
  char* ws = (char*)d_ws;
  // inter (bf16, 16MB) aliases P (f32 partials, 16MB): inter dead before gemm2.
  ushort* inter = (ushort*)(ws);
  float*  P     = (float*)(ws);
  ushort* W1b   = (ushort*)(ws + 16 * MB);
  ushort* W2b   = (ushort*)(ws + 32 * MB);
  ushort* xb    = (ushort*)(ws + 48 * MB);
  ushort* hb    = (ushort*)(ws + 52 * MB);
  char*   S     = ws + 60 * MB;
  float*  t1    = (float*)(S);
  float*  t2    = (float*)(S + 4096);
  float*  b1    = (float*)(S + 8192);
  float*  b2    = (float*)(S + 8192 + 16384);
  float*  parts = (float*)(S + 8192 + 16384 + 8192);

  make_t_kernel<<<2, 256, 0, stream>>>(V, BB_W1, BB_W2, t1, t2);
  make_bias_kernel<<<2, 256, 0, stream>>>(V, BB_b1, Pi_b1, GG_b1, b1_0,
                                          BB_b2, Pi_b2, GG_b2, b2_0, b1, b2);
  cvt_f32_bf16<<<2048, 256, 0, stream>>>((const float4*)x, (ushort4*)xb, 524288);

  ff_pass1<<<1024, 256, 0, stream>>>(Pi_W1, GG_W1, t1, inter, parts);
  ff_pass2<<<256, 1024, 0, stream>>>(inter, W1_0, parts, W1b);
  ff_pass1<<<1024, 256, 0, stream>>>(Pi_W2, GG_W2, t2, inter, parts);
  ff_pass2<<<256, 1024, 0, stream>>>(inter, W2_0, parts, W2b);

  // h = relu(x @ W1^T + b1) -> bf16
  gemm_bt<0><<<dim3(32, 8, 1), 256, 0, stream>>>(xb, W1b, b1, hb, nullptr, 1024, 4096, 2048, 32);
  // out partials = h @ W2^T (split-K2), then out = P0+P1+b2
  gemm_bt<1><<<dim3(16, 8, 2), 256, 0, stream>>>(hb, W2b, nullptr, nullptr, P, 1024, 2048, 4096, 32);
  reduce_out<<<2048, 256, 0, stream>>>((const float4*)P, b2, (float4*)out);
}

// Round 3
// 175.182 us; speedup vs baseline: 1.7613x; 1.0549x over previous
//
#include <hip/hip_runtime.h>
#include <hip/hip_bf16.h>
#include <stdint.h>

// B=1024, D_IN=2048, D_H=4096, D_OUT=2048, D_INT=1024
// L_W = 2^23 for both weight fastfoods; L_b1=4096, L_b2=2048. LL==DD everywhere.

typedef __attribute__((ext_vector_type(8))) short bf16x8;   // 8 bf16 (4 VGPRs)
typedef __attribute__((ext_vector_type(8))) short short8;
typedef __attribute__((ext_vector_type(4))) float f32x4;

__device__ __forceinline__ ushort f2bf(float f) {           // RNE f32->bf16
  union { float f; uint32_t u; } v; v.f = f;
  return (ushort)((v.u + 0x7FFFu + ((v.u >> 16) & 1u)) >> 16);
}
__device__ __forceinline__ float bf2f(ushort u) {
  union { uint32_t u; float f; } v; v.u = (uint32_t)u << 16; return v.f;
}

__device__ __forceinline__ void gload_lds16(const void* g, void* l) {
  __builtin_amdgcn_global_load_lds(
      (const __attribute__((address_space(1))) void*)g,
      (__attribute__((address_space(3))) void*)l, 16, 0, 0);
}

__device__ __forceinline__ void wait_vm16() { asm volatile("s_waitcnt vmcnt(16)" ::: "memory"); }
__device__ __forceinline__ void wait_vm8()  { asm volatile("s_waitcnt vmcnt(8)"  ::: "memory"); }
__device__ __forceinline__ void wait_vm0()  { asm volatile("s_waitcnt vmcnt(0)"  ::: "memory"); }
__device__ __forceinline__ void wait_lgkm0(){ asm volatile("s_waitcnt lgkmcnt(0)" ::: "memory"); }
__device__ __forceinline__ void barrier_raw(){ asm volatile("s_barrier" ::: "memory"); }

template <int NN>
__device__ __forceinline__ void wht_inreg(float* v) {
#pragma unroll
  for (int h = 1; h < NN; h <<= 1)
#pragma unroll
    for (int g = 0; g < NN; g += (h << 1))
#pragma unroll
      for (int k = 0; k < h; ++k) {
        float a = v[g + k], b = v[g + k + h];
        v[g + k] = a + b; v[g + k + h] = a - b;
      }
}

// ---------------- t = WHT_1024(BB[0:1024] * V) for W1 (block 0) and W2 (block 1)
__global__ __launch_bounds__(256) void make_t_kernel(
    const float* __restrict__ V, const float* __restrict__ BB1,
    const float* __restrict__ BB2, float* __restrict__ t1, float* __restrict__ t2) {
  __shared__ float ts[1024];
  const float* BB = blockIdx.x ? BB2 : BB1;
  float* t = blockIdx.x ? t2 : t1;
  int tid = threadIdx.x;
  for (int i = tid; i < 1024; i += 256) ts[i] = BB[i] * V[i];
  for (int st = 0; st < 10; ++st) {
    int half = 1 << st;
    __syncthreads();
    for (int j = tid; j < 512; j += 256) {
      int p = ((j >> st) << (st + 1)) | (j & (half - 1));
      float a = ts[p], b = ts[p + half];
      ts[p] = a + b; ts[p + half] = a - b;
    }
  }
  __syncthreads();
  for (int i = tid; i < 1024; i += 256) t[i] = ts[i];
}

// ---------------- full fastfood for biases: block 0 -> b1 (L=4096), block 1 -> b2 (L=2048)
__global__ __launch_bounds__(256) void make_bias_kernel(
    const float* __restrict__ V,
    const float* __restrict__ BB1, const int* __restrict__ Pi1, const float* __restrict__ GG1, const float* __restrict__ b10,
    const float* __restrict__ BB2, const int* __restrict__ Pi2, const float* __restrict__ GG2, const float* __restrict__ b20,
    float* __restrict__ ob1, float* __restrict__ ob2) {
  __shared__ float ts[1024];
  __shared__ float zs[4096];
  __shared__ float red[4];
  int tid = threadIdx.x;
  int which = blockIdx.x;
  int L = which ? 2048 : 4096;
  const float* BB = which ? BB2 : BB1;
  const int* Pi = which ? Pi2 : Pi1;
  const float* GG = which ? GG2 : GG1;
  const float* b0 = which ? b20 : b10;
  float* ob = which ? ob2 : ob1;

  for (int i = tid; i < 1024; i += 256) ts[i] = BB[i] * V[i];
  for (int st = 0; st < 10; ++st) {
    int half = 1 << st;
    __syncthreads();
    for (int j = tid; j < 512; j += 256) {
      int p = ((j >> st) << (st + 1)) | (j & (half - 1));
      float a = ts[p], b = ts[p + half];
      ts[p] = a + b; ts[p + half] = a - b;
    }
  }
  __syncthreads();
  float gsum = 0.f;
  for (int i = tid; i < L; i += 256) {
    int pi = Pi[i];
    float g = GG[i];
    gsum += g * g;
    zs[i] = ts[pi & 1023] * g;
  }
  for (int o = 32; o > 0; o >>= 1) gsum += __shfl_down(gsum, o);
  if ((tid & 63) == 0) red[tid >> 6] = gsum;
  __syncthreads();
  float ssum = red[0] + red[1] + red[2] + red[3];
  for (int st = 0; (1 << st) < L; ++st) {
    int half = 1 << st;
    __syncthreads();
    for (int j = tid; j < (L >> 1); j += 256) {
      int p = ((j >> st) << (st + 1)) | (j & (half - 1));
      float a = zs[p], b = zs[p + half];
      zs[p] = a + b; zs[p + half] = a - b;
    }
  }
  __syncthreads();
  float scale = rsqrtf((float)L * ssum);
  for (int i = tid; i < L; i += 256) ob[i] = b0[i] + zs[i] * scale;
}

// ---------------- pass 1 (both weights): z = t[Pi&1023]*GG, WHT_8192 on contiguous
// 8192-blocks (bits 0..12) via radix 32(bits3-7)/32(bits8-12)/8(bits0-2) register
// passes; skewed LDS slot = i + (i>>5) keeps all passes <=2-way (free).
// Vectorized int4/float4 gathers, short8 coalesced stores. Per-block GG^2 partial.
__global__ __launch_bounds__(256) void ff_pass1(
    const int* __restrict__ Pi1, const float* __restrict__ GG1,
    const int* __restrict__ Pi2, const float* __restrict__ GG2,
    const float* __restrict__ t1, const float* __restrict__ t2,
    ushort* __restrict__ inter1, ushort* __restrict__ inter2,
    float* __restrict__ partials) {
  __shared__ float ts[1024];
  __shared__ float zs[8448];        // 8192 + skew
  __shared__ float red[4];
  int tid = threadIdx.x;
  int wsel = blockIdx.x >> 10;
  int blk = blockIdx.x & 1023;
  const int* Pi = wsel ? Pi2 : Pi1;
  const float* GG = wsel ? GG2 : GG1;
  const float* t = wsel ? t2 : t1;
  ushort* inter = wsel ? inter2 : inter1;
  size_t base = (size_t)blk * 8192;

  for (int i = tid; i < 1024; i += 256) ts[i] = t[i];
  __syncthreads();

  const int4* Pi4 = (const int4*)(Pi + base);
  const float4* GG4 = (const float4*)(GG + base);
  float gsum = 0.f;
#pragma unroll
  for (int q = 0; q < 8; ++q) {
    int u = (q << 8) + tid;          // 0..2047
    int4 p4 = Pi4[u];
    float4 g4 = GG4[u];
    gsum += g4.x * g4.x + g4.y * g4.y + g4.z * g4.z + g4.w * g4.w;
    int i0 = u << 2;
    float4 z;
    z.x = ts[p4.x & 1023] * g4.x;
    z.y = ts[p4.y & 1023] * g4.y;
    z.z = ts[p4.z & 1023] * g4.z;
    z.w = ts[p4.w & 1023] * g4.w;
    *(float4*)&zs[i0 + (i0 >> 5)] = z;
  }
  for (int o = 32; o > 0; o >>= 1) gsum += __shfl_down(gsum, o);
  if ((tid & 63) == 0) red[tid >> 6] = gsum;
  __syncthreads();
  if (tid == 0) partials[blockIdx.x] = red[0] + red[1] + red[2] + red[3];

  float v[32];
  // pass A: bits 3-7
  {
    int o = (tid & 7) | ((tid >> 3) << 8);
#pragma unroll
    for (int r = 0; r < 32; ++r) { int i = o + (r << 3); v[r] = zs[i + (i >> 5)]; }
    wht_inreg<32>(v);
#pragma unroll
    for (int r = 0; r < 32; ++r) { int i = o + (r << 3); zs[i + (i >> 5)] = v[r]; }
  }
  __syncthreads();
  // pass B: bits 8-12
  {
#pragma unroll
    for (int r = 0; r < 32; ++r) { int i = tid | (r << 8); v[r] = zs[i + (i >> 5)]; }
    wht_inreg<32>(v);
#pragma unroll
    for (int r = 0; r < 32; ++r) { int i = tid | (r << 8); zs[i + (i >> 5)] = v[r]; }
  }
  __syncthreads();
  // pass C: bits 0-2 (4 runs of 8) + coalesced short8 stores
  {
    int tp = ((tid & 63) << 3) | ((tid >> 6) << 11);
#pragma unroll
    for (int j = 0; j < 4; ++j)
#pragma unroll
      for (int k = 0; k < 8; ++k) { int i = tp + (j << 9) + k; v[(j << 3) + k] = zs[i + (i >> 5)]; }
#pragma unroll
    for (int j = 0; j < 4; ++j) wht_inreg<8>(v + (j << 3));
#pragma unroll
    for (int j = 0; j < 4; ++j) {
      short8 s;
#pragma unroll
      for (int k = 0; k < 8; ++k) s[k] = (short)f2bf(v[(j << 3) + k]);
      *(short8*)(inter + base + tp + (j << 9)) = s;
    }
  }
}

// ---------------- pass 2 (both weights): WHT_1024 across stride 8192 (bits 13..22)
// on a [1024 x 32] tile (stride 33), 2 radix-32 register passes + vectorized
// epilogue W = W0 + m5*scale -> bf16 (short8 stores, float4 W0 reads).
__global__ __launch_bounds__(1024) void ff_pass2(
    const ushort* __restrict__ inter1, const ushort* __restrict__ inter2,
    const float* __restrict__ W01, const float* __restrict__ W02,
    const float* __restrict__ partials,
    ushort* __restrict__ W1b, ushort* __restrict__ W2b) {
  __shared__ float tile[1024 * 33];
  __shared__ float red2[16];
  int tid = threadIdx.x;
  int wsel = blockIdx.x >> 8;
  int cb = (blockIdx.x & 255) << 5;
  const ushort* inter = wsel ? inter2 : inter1;
  const float* W0 = wsel ? W02 : W01;
  ushort* Wb = wsel ? W2b : W1b;

  float s = partials[(wsel << 10) + tid];
  for (int o = 32; o > 0; o >>= 1) s += __shfl_down(s, o);
  if ((tid & 63) == 0) red2[tid >> 6] = s;
  // load tile: 4096 short8 units (16B/lane)
#pragma unroll
  for (int it = 0; it < 4; ++it) {
    int u = (it << 10) + tid;
    int row = u >> 2, c8 = (u & 3) << 3;
    short8 d = *(const short8*)(inter + ((size_t)row << 13) + cb + c8);
    float* tp = &tile[row * 33 + c8];
#pragma unroll
    for (int k = 0; k < 8; ++k) tp[k] = bf2f((ushort)d[k]);
  }
  __syncthreads();
  float ssum = 0.f;
#pragma unroll
  for (int k = 0; k < 16; ++k) ssum += red2[k];
  float sc = rsqrtf(8388608.f * ssum);

  float v[32];
  int c = tid & 31, g = tid >> 5;
  // pass A: row bits 0-4
#pragma unroll
  for (int r = 0; r < 32; ++r) v[r] = tile[((g << 5) + r) * 33 + c];
  wht_inreg<32>(v);
#pragma unroll
  for (int r = 0; r < 32; ++r) tile[((g << 5) + r) * 33 + c] = v[r];
  __syncthreads();
  // pass B: row bits 5-9
#pragma unroll
  for (int r = 0; r < 32; ++r) v[r] = tile[((r << 5) + g) * 33 + c];
  wht_inreg<32>(v);
#pragma unroll
  for (int r = 0; r < 32; ++r) tile[((r << 5) + g) * 33 + c] = v[r];
  __syncthreads();
  // epilogue: vectorized (float4 W0 reads, short8 stores)
#pragma unroll
  for (int it = 0; it < 4; ++it) {
    int u = (it << 10) + tid;
    int row = u >> 2, c8 = (u & 3) << 3;
    size_t gbase = ((size_t)row << 13) + cb + c8;
    const float* tp = &tile[row * 33 + c8];
    short8 o8;
#pragma unroll
    for (int k = 0; k < 8; ++k) o8[k] = (short)f2bf(tp[k] * sc + W0[gbase + k]);
    *(short8*)(Wb + gbase) = o8;
  }
}

// ---------------- x (f32) -> bf16
__global__ __launch_bounds__(256) void cvt_f32_bf16(
    const float4* __restrict__ in, ushort4* __restrict__ out, int n4) {
  int i = blockIdx.x * 256 + threadIdx.x;
  if (i < n4) {
    float4 v = in[i];
    ushort4 o;
    o.x = f2bf(v.x); o.y = f2bf(v.y); o.z = f2bf(v.z); o.w = f2bf(v.w);
    out[i] = o;
  }
}

// ---------------- C = A * B^T  (A: MxK bf16 row-major, B: NxK bf16 row-major)
// 128x128 tile, BK=64, 4 waves (2x2), each wave 64x64 = 4x4 frags of 16x16x32.
// 4-buffer LDS pipeline, 3-deep global_load_lds prefetch, counted vmcnt + raw
// s_barrier (one barrier per K-step; never vmcnt(0) in steady state).
// WAR safety: STAGE(t+3) targets buf (t+3)&3 == (t-1)&3, whose ds_reads all
// waves completed before this iteration's barrier (lgkm0 before MFMA pins it).
// Both-sides XOR swizzle (src col8 ^= row&7 on global addr, same XOR on read).
// EPI==0: C = bf16(relu(acc + bias)) -> Cb ;  EPI==1: f32 partial -> Cf[z]
template <int EPI, int NT>
__global__ __launch_bounds__(256) void gemm_bt(
    const ushort* __restrict__ A, const ushort* __restrict__ B,
    const float* __restrict__ bias, ushort* __restrict__ Cb, float* __restrict__ Cf,
    int M, int N, int K) {
  __shared__ ushort As[4][8192];
  __shared__ ushort Bs[4][8192];
  const int tid = threadIdx.x;
  const int w = tid >> 6, l = tid & 63;
  const int wr = w >> 1, wc = w & 1;
  const int brow = blockIdx.y << 7, bcol = blockIdx.x << 7;
  const int lrow = l >> 3;                       // row within 8-row chunk
  const int csrc = ((l & 7) ^ lrow) << 3;        // swizzled source col (ushort)
  const int l15 = l & 15;
  const int x7 = l15 & 7;
  const int kb = blockIdx.z * (NT << 6);
  f32x4 acc[4][4] = {};

  const ushort* pa = A + (size_t)(brow + (w << 5) + lrow) * K + kb + csrc;
  const ushort* pb = B + (size_t)(bcol + (w << 5) + lrow) * K + kb + csrc;
  const size_t K8 = (size_t)K << 3;

#define STAGE(buf, tt)                                                      \
  {                                                                         \
    const ushort* qa = pa + ((tt) << 6);                                    \
    const ushort* qb = pb + ((tt) << 6);                                    \
    _Pragma("unroll")                                                       \
    for (int i = 0; i < 4; ++i) {                                           \
      gload_lds16(qa + K8 * i, &As[buf][(((w << 2) + i) << 9)]);            \
      gload_lds16(qb + K8 * i, &Bs[buf][(((w << 2) + i) << 9)]);            \
    }                                                                       \
  }

  STAGE(0, 0); STAGE(1, 1); STAGE(2, 2);      // 24 outstanding per wave
  for (int t = 0; t < NT; ++t) {
    if (t < NT - 2) wait_vm16();              // stage t done, t+1/t+2 in flight
    else if (t == NT - 2) wait_vm8();
    else wait_vm0();
    barrier_raw();
    if (t + 3 < NT) STAGE((t + 3) & 3, t + 3);
    const ushort* Acur = As[t & 3];
    const ushort* Bcur = Bs[t & 3];
    bf16x8 af[2][4], bfr[2][4];
#pragma unroll
    for (int kk = 0; kk < 2; ++kk) {
      int c8 = (kk << 2) + (l >> 4);
#pragma unroll
      for (int m = 0; m < 4; ++m)
        af[kk][m] = *(const bf16x8*)&Acur[(((wr << 6) + (m << 4) + l15) << 6) + ((c8 ^ x7) << 3)];
#pragma unroll
      for (int n = 0; n < 4; ++n)
        bfr[kk][n] = *(const bf16x8*)&Bcur[(((wc << 6) + (n << 4) + l15) << 6) + ((c8 ^ x7) << 3)];
    }
    wait_lgkm0();                              // reads complete before next barrier
#pragma unroll
    for (int kk = 0; kk < 2; ++kk)
#pragma unroll
      for (int m = 0; m < 4; ++m)
#pragma unroll
        for (int n = 0; n < 4; ++n)
          acc[m][n] = __builtin_amdgcn_mfma_f32_16x16x32_bf16(af[kk][m], bfr[kk][n], acc[m][n], 0, 0, 0);
  }
#undef STAGE

  if (EPI == 0) {
#pragma unroll
    for (int n = 0; n < 4; ++n) {
      int col = bcol + (wc << 6) + (n << 4) + l15;
      float bv = bias[col];
#pragma unroll
      for (int m = 0; m < 4; ++m) {
        int row0 = brow + (wr << 6) + (m << 4) + ((l >> 4) << 2);
#pragma unroll
        for (int j = 0; j < 4; ++j) {
          float vv = fmaxf(acc[m][n][j] + bv, 0.f);
          Cb[(size_t)(row0 + j) * N + col] = f2bf(vv);
        }
      }
    }
  } else {
    float* outp = Cf + (size_t)blockIdx.z * M * N;
#pragma unroll
    for (int n = 0; n < 4; ++n) {
      int col = bcol + (wc << 6) + (n << 4) + l15;
#pragma unroll
      for (int m = 0; m < 4; ++m) {
        int row0 = brow + (wr << 6) + (m << 4) + ((l >> 4) << 2);
#pragma unroll
        for (int j = 0; j < 4; ++j)
          outp[(size_t)(row0 + j) * N + col] = acc[m][n][j];
      }
    }
  }
}

// ---------------- out = P0 + P1 + b2   (1024x2048 f32, vectorized f4)
__global__ __launch_bounds__(256) void reduce_out(
    const float4* __restrict__ P, const float* __restrict__ b2,
    float4* __restrict__ out) {
  int i = blockIdx.x * 256 + threadIdx.x;         // 524288 f4
  float4 a = P[i], b = P[i + 524288];
  const float4 bb = *(const float4*)(b2 + ((i & 511) << 2));
  float4 o;
  o.x = a.x + b.x + bb.x; o.y = a.y + b.y + bb.y;
  o.z = a.z + b.z + bb.z; o.w = a.w + b.w + bb.w;
  out[i] = o;
}

extern "C" void kernel_launch(void* const* d_in, const int* in_sizes, int n_in,
                              void* d_out, int out_size, void* d_ws, size_t ws_size,
                              hipStream_t stream) {
  const float* x     = (const float*)d_in[0];
  const float* V     = (const float*)d_in[1];
  const float* W1_0  = (const float*)d_in[2];
  const float* b1_0  = (const float*)d_in[3];
  const float* W2_0  = (const float*)d_in[4];
  const float* b2_0  = (const float*)d_in[5];
  const float* BB_W1 = (const float*)d_in[6];
  const int*   Pi_W1 = (const int*)d_in[7];
  const float* GG_W1 = (const float*)d_in[8];
  const float* BB_b1 = (const float*)d_in[9];
  const int*   Pi_b1 = (const int*)d_in[10];
  const float* GG_b1 = (const float*)d_in[11];
  const float* BB_W2 = (const float*)d_in[12];
  const int*   Pi_W2 = (const int*)d_in[13];
  const float* GG_W2 = (const float*)d_in[14];
  const float* BB_b2 = (const float*)d_in[15];
  const int*   Pi_b2 = (const int*)d_in[16];
  const float* GG_b2 = (const float*)d_in[17];
  float* out = (float*)d_out;

  const size_t MB = 1048576ull;
  char* ws = (char*)d_ws;
  // inter1 (bf16, 16MB) aliases P (f32 partials, 16MB): inter1 dead before gemm2.
  ushort* inter1 = (ushort*)(ws);
  float*  P      = (float*)(ws);
  ushort* inter2 = (ushort*)(ws + 16 * MB);
  ushort* W1b    = (ushort*)(ws + 32 * MB);
  ushort* W2b    = (ushort*)(ws + 48 * MB);
  ushort* xb     = (ushort*)(ws + 64 * MB);
  ushort* hb     = (ushort*)(ws + 68 * MB);
  char*   S      = ws + 76 * MB;
  float*  t1     = (float*)(S);
  float*  t2     = (float*)(S + 4096);
  float*  b1     = (float*)(S + 8192);
  float*  b2     = (float*)(S + 8192 + 16384);
  float*  parts  = (float*)(S + 8192 + 16384 + 8192);   // 2048 floats

  make_t_kernel<<<2, 256, 0, stream>>>(V, BB_W1, BB_W2, t1, t2);
  make_bias_kernel<<<2, 256, 0, stream>>>(V, BB_b1, Pi_b1, GG_b1, b1_0,
                                          BB_b2, Pi_b2, GG_b2, b2_0, b1, b2);
  cvt_f32_bf16<<<2048, 256, 0, stream>>>((const float4*)x, (ushort4*)xb, 524288);

  ff_pass1<<<2048, 256, 0, stream>>>(Pi_W1, GG_W1, Pi_W2, GG_W2, t1, t2,
                                     inter1, inter2, parts);
  ff_pass2<<<512, 1024, 0, stream>>>(inter1, inter2, W1_0, W2_0, parts, W1b, W2b);

  // h = relu(x @ W1^T + b1) -> bf16
  gemm_bt<0, 32><<<dim3(32, 8, 1), 256, 0, stream>>>(xb, W1b, b1, hb, nullptr, 1024, 4096, 2048);
  // out partials = h @ W2^T (split-K2), then out = P0+P1+b2
  gemm_bt<1, 32><<<dim3(16, 8, 2), 256, 0, stream>>>(hb, W2b, nullptr, nullptr, P, 1024, 2048, 4096);
  reduce_out<<<2048, 256, 0, stream>>>((const float4*)P, b2, (float4*)out);
}